// Round 12
// baseline (173.960 us; speedup 1.0000x reference)
//
#include <hip/hip_runtime.h>
#include <math.h>

#define V      21841
#define TOPK   250
#define NT     1024
#define NWAVE  (NT / 64)     // 16
#define ROWS   8             // rows per block; grid = 2048/8 = 256 = 1 block/CU
#define NRQ    6             // float4 regs per row per thread: 5*1024=5120 always valid, q=5 masked
#define SEGCAP 128           // per-wave candidates (expect ~31 +/- 5.5)
#define TF0    8.0f          // fixed candidate threshold: 250th/21841 of N(0,16) = 9.17 +/- 0.10;
                             // ~497+/-22 candidates/row. Exact fallback if out of bounds.

typedef float floatx4 __attribute__((ext_vector_type(4)));

__device__ __forceinline__ float clipf(float v) {
    return fminf(fmaxf(v, -1e15f), 1e15f);
}
// order-preserving float->uint key (ascending uint == ascending float)
__device__ __forceinline__ unsigned enc(float v) {
    unsigned b = __float_as_uint(v);
    return (b & 0x80000000u) ? ~b : (b | 0x80000000u);
}
__device__ __forceinline__ float dec(unsigned k) {
    unsigned b = (k & 0x80000000u) ? (k & 0x7FFFFFFFu) : ~k;
    return __uint_as_float(b);
}

// wave-synchronous select over a 256-bin hist; result broadcast to all 64 lanes.
__device__ __forceinline__ void wsel64(const unsigned* hist, unsigned kr,
                                       unsigned& bin, unsigned& newkr) {
    const int lane = threadIdx.x & 63;
    uint4 h = reinterpret_cast<const uint4*>(hist)[lane];
    unsigned lsum = h.x + h.y + h.z + h.w;
    unsigned suf = lsum;
#pragma unroll
    for (int off = 1; off < 64; off <<= 1) {
        unsigned t = __shfl_down(suf, off);
        if (lane + off < 64) suf += t;
    }
    bool cross = (suf >= kr) && (suf - lsum < kr);
    unsigned long long cm = __ballot(cross);
    int cl = (int)__ffsll(cm) - 1;
    unsigned b = 0, nk = 0;
    if (lane == cl) {
        unsigned hb[4] = {h.x, h.y, h.z, h.w};
        unsigned cum = suf - lsum;
        int q = 3;
        for (; q >= 0; --q) { cum += hb[q]; if (cum >= kr) break; }
        b = (unsigned)((lane << 2) + q);
        nk = kr - (cum - hb[q]);
    }
    bin = (unsigned)__shfl((int)b, cl);
    newkr = (unsigned)__shfl((int)nk, cl);
}

__global__ __launch_bounds__(NT, 4) void lnclamp_pipe(const float* __restrict__ in,
                                                      float* __restrict__ out,
                                                      int nrows) {
    __shared__ __align__(16) unsigned hist[256];
    __shared__ __align__(16) unsigned cand[NWAVE][SEGCAP];
    __shared__ int cnt[NWAVE];
    __shared__ unsigned sh_bin, sh_krem;
    __shared__ double redS[NWAVE], redS2[NWAVE];
    __shared__ float sh_mean, sh_istd;

    const int tid = threadIdx.x, lane = tid & 63, wid = tid >> 6;
    const int rbase = blockIdx.x * ROWS;

    floatx4 rA[NRQ], rB[NRQ];
    float hvA = 0.f, tvA = 0.f, hvB = 0.f, tvB = 0.f;

    // issue nt-loads of one row into a register set (never re-read from cache)
    auto LOADROW = [&](floatx4 (&r)[NRQ], float& hv, float& tv, int row) {
        const float* rp = in + (size_t)row * V;
        const int first = (4 - (row & 3)) & 3;
        const int nvec = (V - first) >> 2;
        const int tail_ = first + (nvec << 2);
        const floatx4* vp = reinterpret_cast<const floatx4*>(rp + first);
#pragma unroll
        for (int q = 0; q < NRQ - 1; ++q)
            r[q] = __builtin_nontemporal_load(vp + tid + q * NT);
        {
            int j = tid + (NRQ - 1) * NT;
            if (j < nvec) r[NRQ - 1] = __builtin_nontemporal_load(vp + j);
        }
        hv = (tid < first) ? rp[tid] : 0.0f;
        int ti = tail_ + tid;
        tv = (ti < V) ? rp[ti] : 0.0f;
    };

    auto PROCESS = [&](floatx4 (&r)[NRQ], float hv, float tv, int row) {
        const float* rp = in + (size_t)row * V;
        float* op = out + (size_t)row * V;
        const int first = (4 - (row & 3)) & 3;
        const int nvec = (V - first) >> 2;
        const int tail_ = first + (nvec << 2);
        floatx4* ovp = reinterpret_cast<floatx4*>(op + first);
        const int ti = tail_ + tid;

        if (tid < NWAVE) cnt[tid] = 0;
        __syncthreads();                        // barrier 1: cnt zeroed

        // emit candidates from registers
        auto emit = [&](float v) {
            if (v >= TF0) {
                int p = atomicAdd(&cnt[wid], 1);
                if (p < SEGCAP) cand[wid][p] = enc(clipf(v));
            }
        };
        if (tid < first) emit(hv);
#pragma unroll
        for (int q = 0; q < NRQ - 1; ++q) {
            emit(r[q].x); emit(r[q].y); emit(r[q].z); emit(r[q].w);
        }
        {
            int j = tid + (NRQ - 1) * NT;
            if (j < nvec) { emit(r[NRQ-1].x); emit(r[NRQ-1].y); emit(r[NRQ-1].z); emit(r[NRQ-1].w); }
        }
        if (ti < V) emit(tv);
        __syncthreads();                        // barrier 2: all candidates in LDS

        int ncand = 0;
        bool segok = true;
#pragma unroll
        for (int w = 0; w < NWAVE; ++w) {
            ncand += cnt[w];
            segok = segok && (cnt[w] <= SEGCAP);
        }
        const bool fastok = segok && (ncand >= TOPK);   // block-uniform

        if (fastok) {
            if (wid == 0) {                     // single-wave radix + stats
                unsigned prefix = 0, pmask = 0, kr = TOPK;
#pragma unroll
                for (int level = 0; level < 4; ++level) {
                    const int shift = 24 - 8 * level;
                    reinterpret_cast<uint4*>(hist)[lane] = make_uint4(0u,0u,0u,0u);
                    __builtin_amdgcn_wave_barrier();
#pragma unroll
                    for (int w = 0; w < NWAVE; ++w) {
                        const int c = cnt[w];
                        for (int i = lane; i < c; i += 64) {
                            unsigned k = cand[w][i];
                            if ((k & pmask) == prefix) atomicAdd(&hist[(k >> shift) & 255u], 1u);
                        }
                    }
                    __builtin_amdgcn_wave_barrier();
                    unsigned bin, nk;
                    wsel64(hist, kr, bin, nk);
                    prefix |= bin << shift;
                    pmask |= 255u << shift;
                    kr = nk;
                }
                const unsigned T = prefix;
                const unsigned krem = kr;
                double s = 0.0, s2 = 0.0;
#pragma unroll
                for (int w = 0; w < NWAVE; ++w) {
                    const int c = cnt[w];
                    for (int i = lane; i < c; i += 64) {
                        unsigned k = cand[w][i];
                        if (k > T) { double dv = (double)dec(k); s += dv; s2 += dv * dv; }
                    }
                }
                for (int off = 32; off > 0; off >>= 1) {
                    s += __shfl_down(s, off); s2 += __shfl_down(s2, off);
                }
                if (lane == 0) {
                    const double vT = (double)dec(T);
                    double S = s + (double)krem * vT;
                    double S2 = s2 + (double)krem * vT * vT;
                    const double mean = S / (double)TOPK;
                    const double var = (S2 - S * S / (double)TOPK) / (double)(TOPK - 1);
                    sh_mean = (float)mean;
                    sh_istd = (float)(1.0 / sqrt(var + 1e-8));
                }
            }
        } else {
            // exact fallback: block-wide 4-pass MSB radix from global (any data)
            unsigned prefix = 0, pmask = 0, kr = TOPK;
            for (int level = 0; level < 4; ++level) {
                const int shift = 24 - 8 * level;
                __syncthreads();
                if (tid < 256) hist[tid] = 0;
                __syncthreads();
                for (int i = tid; i < V; i += NT) {
                    unsigned k = enc(clipf(rp[i]));
                    if ((k & pmask) == prefix) atomicAdd(&hist[(k >> shift) & 255u], 1u);
                }
                __syncthreads();
                if (tid < 64) {
                    unsigned bin, nk;
                    wsel64(hist, kr, bin, nk);
                    if (lane == 0) { sh_bin = bin; sh_krem = nk; }
                }
                __syncthreads();
                prefix |= sh_bin << shift;
                pmask |= 255u << shift;
                kr = sh_krem;
            }
            const unsigned T = prefix;
            const unsigned krem = kr;
            double s = 0.0, s2 = 0.0;
            for (int i = tid; i < V; i += NT) {
                float v = clipf(rp[i]);
                if (enc(v) > T) { double dv = v; s += dv; s2 += dv * dv; }
            }
            for (int off = 32; off > 0; off >>= 1) {
                s += __shfl_down(s, off); s2 += __shfl_down(s2, off);
            }
            if (lane == 0) { redS[wid] = s; redS2[wid] = s2; }
            __syncthreads();
            if (tid == 0) {
                double S = 0.0, S2 = 0.0;
                for (int w = 0; w < NWAVE; ++w) { S += redS[w]; S2 += redS2[w]; }
                const double vT = (double)dec(T);
                S += (double)krem * vT;
                S2 += (double)krem * vT * vT;
                const double mean = S / (double)TOPK;
                const double var = (S2 - S * S / (double)TOPK) / (double)(TOPK - 1);
                sh_mean = (float)mean;
                sh_istd = (float)(1.0 / sqrt(var + 1e-8));
            }
        }
        __syncthreads();                        // barrier 3: stats ready

        const float istd = sh_istd;
        const float c1 = -sh_mean * istd - 1.0f;   // n = clip(v)*istd + c1
        // GELU tanh-form via exp: g = n*(1-r2), r2 = 1/(1+exp(1.5957691*(n+0.044715*n^3)))
        auto outf = [&](float v) -> float {
            float n = fmaf(clipf(v), istd, c1);
            float t1 = n * n;
            float t3 = fmaf(t1 * n, 0.044715f, n);
            float e = __expf(1.59576912160573f * t3);
            float r2 = __frcp_rn(1.0f + e);
            float w = fmaf(-0.4f, r2, 0.4f);
            return n * w;
        };
        if (tid < first) op[tid] = outf(hv);
#pragma unroll
        for (int q = 0; q < NRQ - 1; ++q) {
            floatx4 o;
            o.x = outf(r[q].x); o.y = outf(r[q].y); o.z = outf(r[q].z); o.w = outf(r[q].w);
            __builtin_nontemporal_store(o, ovp + tid + q * NT);
        }
        {
            int j = tid + (NRQ - 1) * NT;
            if (j < nvec) {
                floatx4 o;
                o.x = outf(r[NRQ-1].x); o.y = outf(r[NRQ-1].y);
                o.z = outf(r[NRQ-1].z); o.w = outf(r[NRQ-1].w);
                __builtin_nontemporal_store(o, ovp + j);
            }
        }
        if (ti < V) op[ti] = outf(tv);
    };

    // ---- software pipeline: next row's loads in flight during current row's work ----
    if (rbase >= nrows) return;
    LOADROW(rA, hvA, tvA, rbase);
#pragma unroll 1
    for (int t = 0; t < ROWS; t += 2) {
        if (rbase + t >= nrows) break;
        if (rbase + t + 1 < nrows) LOADROW(rB, hvB, tvB, rbase + t + 1);
        PROCESS(rA, hvA, tvA, rbase + t);
        if (rbase + t + 1 >= nrows) break;
        if (rbase + t + 2 < nrows) LOADROW(rA, hvA, tvA, rbase + t + 2);
        PROCESS(rB, hvB, tvB, rbase + t + 1);
    }
}

extern "C" void kernel_launch(void* const* d_in, const int* in_sizes, int n_in,
                              void* d_out, int out_size, void* d_ws, size_t ws_size,
                              hipStream_t stream) {
    const float* in = (const float*)d_in[0];
    float* out = (float*)d_out;
    const int rows = out_size / V;             // 2048
    const int nb = (rows + ROWS - 1) / ROWS;   // 256 -> one block per CU
    hipLaunchKernelGGL(lnclamp_pipe, dim3(nb), dim3(NT), 0, stream, in, out, rows);
}

// Round 13
// 98.032 us; speedup vs baseline: 1.7745x; 1.7745x over previous
//
#include <hip/hip_runtime.h>
#include <math.h>

#define V      21841
#define TOPK   250
#define NT     256
#define NWAVE  (NT / 64)
#define NR     22           // ceil(5460 float4 / 256 threads)
#define SEGCAP 512          // per-wave candidate segment (expect ~125 +/- 11 per wave)
#define NCH    6            // map-kernel chunks per row: 6*256*4 = 6144 >= 5460 float4
#define TF0    8.0f         // fixed candidate threshold: 250th/21841 of N(0,16) = 9.17 +/- 0.10;
                            // TF0=8.0 -> ~497+/-22 candidates. Fallback if out of bounds.

typedef float floatx4 __attribute__((ext_vector_type(4)));

__device__ __forceinline__ float clipf(float v) {
    return fminf(fmaxf(v, -1e15f), 1e15f);
}
// order-preserving float->uint key (ascending uint == ascending float)
__device__ __forceinline__ unsigned enc(float v) {
    unsigned b = __float_as_uint(v);
    return (b & 0x80000000u) ? ~b : (b | 0x80000000u);
}
__device__ __forceinline__ float dec(unsigned k) {
    unsigned b = (k & 0x80000000u) ? (k & 0x7FFFFFFFu) : ~k;
    return __uint_as_float(b);
}

// wave-synchronous select over a 256-bin hist; result broadcast to all 64 lanes.
__device__ __forceinline__ void wsel64(const unsigned* hist, unsigned kr,
                                       unsigned& bin, unsigned& newkr) {
    const int lane = threadIdx.x & 63;
    uint4 h = reinterpret_cast<const uint4*>(hist)[lane];
    unsigned lsum = h.x + h.y + h.z + h.w;
    unsigned suf = lsum;
#pragma unroll
    for (int off = 1; off < 64; off <<= 1) {
        unsigned t = __shfl_down(suf, off);
        if (lane + off < 64) suf += t;
    }
    bool cross = (suf >= kr) && (suf - lsum < kr);
    unsigned long long cm = __ballot(cross);
    int cl = (int)__ffsll(cm) - 1;
    unsigned b = 0, nk = 0;
    if (lane == cl) {
        unsigned hb[4] = {h.x, h.y, h.z, h.w};
        unsigned cum = suf - lsum;
        int q = 3;
        for (; q >= 0; --q) { cum += hb[q]; if (cum >= kr) break; }
        b = (unsigned)((lane << 2) + q);
        nk = kr - (cum - hb[q]);
    }
    bin = (unsigned)__shfl((int)b, cl);
    newkr = (unsigned)__shfl((int)nk, cl);
}

// ---------------- K1: read-only stats kernel (fills L3 for K2) ----------------
__global__ __launch_bounds__(NT, 4) void stats_kernel(const float* __restrict__ in,
                                                      float2* __restrict__ stats) {
    __shared__ __align__(16) unsigned hist[256];
    __shared__ __align__(16) unsigned cand[NWAVE][SEGCAP];
    __shared__ int cnt[NWAVE];
    __shared__ unsigned sh_bin, sh_krem;
    __shared__ double redS[NWAVE], redS2[NWAVE];

    const int row = blockIdx.x, tid = threadIdx.x, lane = tid & 63, wid = tid >> 6;
    const float* rp = in + (size_t)row * V;

    const int first = (4 - (row & 3)) & 3;   // 16B alignment phase (V % 4 == 1)
    const int nvec = (V - first) >> 2;
    const int tail = first + (nvec << 2);
    const floatx4* vp = reinterpret_cast<const floatx4*>(rp + first);

    // load row into registers with REGULAR loads (populate L3 for the map kernel)
    floatx4 r[NR];
#pragma unroll
    for (int q = 0; q < NR - 1; ++q)          // q<=20: tid+q*NT <= 5375 < nvec always
        r[q] = vp[tid + q * NT];
    {
        int j = tid + (NR - 1) * NT;
        if (j < nvec) r[NR - 1] = vp[j];
    }
    float hv = (tid < first) ? rp[tid] : 0.0f;
    const int ti = tail + tid;
    float tv = (ti < V) ? rp[ti] : 0.0f;

    if (tid < NWAVE) cnt[tid] = 0;
    __syncthreads();

    auto emit = [&](float v) {
        if (v >= TF0) {
            int p = atomicAdd(&cnt[wid], 1);
            if (p < SEGCAP) cand[wid][p] = enc(clipf(v));
        }
    };
    if (tid < first) emit(hv);
#pragma unroll
    for (int q = 0; q < NR - 1; ++q) {
        emit(r[q].x); emit(r[q].y); emit(r[q].z); emit(r[q].w);
    }
    {
        int j = tid + (NR - 1) * NT;
        if (j < nvec) { emit(r[NR-1].x); emit(r[NR-1].y); emit(r[NR-1].z); emit(r[NR-1].w); }
    }
    if (ti < V) emit(tv);
    __syncthreads();

    int ncand = 0;
    bool segok = true;
#pragma unroll
    for (int w = 0; w < NWAVE; ++w) {
        ncand += cnt[w];
        segok = segok && (cnt[w] <= SEGCAP);
    }
    const bool fastok = segok && (ncand >= TOPK);   // block-uniform

    if (fastok) {
        if (wid == 0) {   // single-wave exact radix + stats, no block barriers
            unsigned prefix = 0, pmask = 0, kr = TOPK;
#pragma unroll
            for (int level = 0; level < 4; ++level) {
                const int shift = 24 - 8 * level;
                reinterpret_cast<uint4*>(hist)[lane] = make_uint4(0u, 0u, 0u, 0u);
                __builtin_amdgcn_wave_barrier();
#pragma unroll
                for (int w = 0; w < NWAVE; ++w) {
                    const int c = cnt[w];
                    for (int i = lane; i < c; i += 64) {
                        unsigned k = cand[w][i];
                        if ((k & pmask) == prefix) atomicAdd(&hist[(k >> shift) & 255u], 1u);
                    }
                }
                __builtin_amdgcn_wave_barrier();
                unsigned bin, nk;
                wsel64(hist, kr, bin, nk);
                prefix |= bin << shift;
                pmask |= 255u << shift;
                kr = nk;
            }
            const unsigned T = prefix;
            const unsigned krem = kr;
            double s = 0.0, s2 = 0.0;
#pragma unroll
            for (int w = 0; w < NWAVE; ++w) {
                const int c = cnt[w];
                for (int i = lane; i < c; i += 64) {
                    unsigned k = cand[w][i];
                    if (k > T) { double dv = (double)dec(k); s += dv; s2 += dv * dv; }
                }
            }
            for (int off = 32; off > 0; off >>= 1) {
                s += __shfl_down(s, off); s2 += __shfl_down(s2, off);
            }
            if (lane == 0) {
                const double vT = (double)dec(T);
                double S = s + (double)krem * vT;
                double S2 = s2 + (double)krem * vT * vT;
                const double mean = S / (double)TOPK;
                const double var = (S2 - S * S / (double)TOPK) / (double)(TOPK - 1);
                stats[row] = make_float2((float)mean, (float)(1.0 / sqrt(var + 1e-8)));
            }
        }
    } else {
        // exact fallback: block-wide 4-pass MSB radix from global (any data)
        unsigned prefix = 0, pmask = 0, kr = TOPK;
        for (int level = 0; level < 4; ++level) {
            const int shift = 24 - 8 * level;
            __syncthreads();
            hist[tid] = 0;
            __syncthreads();
            for (int i = tid; i < V; i += NT) {
                unsigned k = enc(clipf(rp[i]));
                if ((k & pmask) == prefix) atomicAdd(&hist[(k >> shift) & 255u], 1u);
            }
            __syncthreads();
            if (tid < 64) {
                unsigned bin, nk;
                wsel64(hist, kr, bin, nk);
                if (lane == 0) { sh_bin = bin; sh_krem = nk; }
            }
            __syncthreads();
            prefix |= sh_bin << shift;
            pmask |= 255u << shift;
            kr = sh_krem;
        }
        const unsigned T = prefix;
        const unsigned krem = kr;
        double s = 0.0, s2 = 0.0;
        for (int i = tid; i < V; i += NT) {
            float v = clipf(rp[i]);
            if (enc(v) > T) { double dv = v; s += dv; s2 += dv * dv; }
        }
        for (int off = 32; off > 0; off >>= 1) {
            s += __shfl_down(s, off); s2 += __shfl_down(s2, off);
        }
        if (lane == 0) { redS[wid] = s; redS2[wid] = s2; }
        __syncthreads();
        if (tid == 0) {
            double S = 0.0, S2 = 0.0;
            for (int w = 0; w < NWAVE; ++w) { S += redS[w]; S2 += redS2[w]; }
            const double vT = (double)dec(T);
            S += (double)krem * vT;
            S2 += (double)krem * vT * vT;
            const double mean = S / (double)TOPK;
            const double var = (S2 - S * S / (double)TOPK) / (double)(TOPK - 1);
            stats[row] = make_float2((float)mean, (float)(1.0 / sqrt(var + 1e-8)));
        }
    }
}

// ---------------- K2: streaming map; reads are L3 hits, writes HBM ----------------
__global__ __launch_bounds__(NT) void map_kernel(const float* __restrict__ in,
                                                 const float2* __restrict__ stats,
                                                 float* __restrict__ out) {
    const int row = blockIdx.y, c = blockIdx.x, tid = threadIdx.x;
    const float* rp = in + (size_t)row * V;
    float* op = out + (size_t)row * V;
    const float2 ms = stats[row];
    const float istd = ms.y;
    const float c1 = -ms.x * istd - 1.0f;     // n = clip(v)*istd + c1

    // GELU tanh-form via exp: g = n*(1-r2), r2 = 1/(1+exp(1.5957691*(n+0.044715*n^3)))
    auto outf = [&](float v) -> float {
        float n = fmaf(clipf(v), istd, c1);
        float t1 = n * n;
        float t3 = fmaf(t1 * n, 0.044715f, n);
        float e = __expf(1.59576912160573f * t3);
        float r2 = __frcp_rn(1.0f + e);
        float w = fmaf(-0.4f, r2, 0.4f);
        return n * w;
    };

    const int first = (4 - (row & 3)) & 3;
    const int nvec = (V - first) >> 2;
    const floatx4* vp = reinterpret_cast<const floatx4*>(rp + first);
    floatx4* ovp = reinterpret_cast<floatx4*>(op + first);

    if (c == 0 && tid < first) op[tid] = outf(rp[tid]);
    if (c == NCH - 1) {
        const int tail = first + (nvec << 2);
        int i = tail + tid;
        if (i < V) op[i] = outf(rp[i]);
    }
    const int base = c * (NT * 4) + tid;
    // batch the 4 loads for MLP, then compute+store
    floatx4 r[4];
    bool ok[4];
#pragma unroll
    for (int q = 0; q < 4; ++q) {
        int j = base + q * NT;
        ok[q] = j < nvec;
        if (ok[q]) r[q] = vp[j];
    }
#pragma unroll
    for (int q = 0; q < 4; ++q) {
        if (ok[q]) {
            floatx4 o;
            o.x = outf(r[q].x);
            o.y = outf(r[q].y);
            o.z = outf(r[q].z);
            o.w = outf(r[q].w);
            __builtin_nontemporal_store(o, ovp + base + q * NT);
        }
    }
}

extern "C" void kernel_launch(void* const* d_in, const int* in_sizes, int n_in,
                              void* d_out, int out_size, void* d_ws, size_t ws_size,
                              hipStream_t stream) {
    const float* in = (const float*)d_in[0];
    float* out = (float*)d_out;
    float2* stats = (float2*)d_ws;
    const int rows = out_size / V;   // 2048
    hipLaunchKernelGGL(stats_kernel, dim3(rows), dim3(NT), 0, stream, in, stats);
    hipLaunchKernelGGL(map_kernel, dim3(NCH, rows), dim3(NT), 0, stream, in, stats, out);
}

// Round 14
// 88.054 us; speedup vs baseline: 1.9756x; 1.1133x over previous
//
#include <hip/hip_runtime.h>
#include <math.h>

#define V      21841
#define TOPK   250
#define NT     256
#define NWAVE  (NT / 64)
#define NR     22           // ceil(5460 float4 / 256 threads)
#define SEGCAP 512          // per-wave candidate segment (expect ~125 +/- 11 per wave)
#define TF0    8.0f         // fixed candidate threshold: 250th/21841 of N(0,16) = 9.17 +/- 0.10;
                            // ~497+/-22 candidates/row. Exact fallback if out of bounds.

typedef float floatx4 __attribute__((ext_vector_type(4)));

__device__ __forceinline__ float clipf(float v) {
    return fminf(fmaxf(v, -1e15f), 1e15f);
}
// order-preserving float->uint key (ascending uint == ascending float)
__device__ __forceinline__ unsigned enc(float v) {
    unsigned b = __float_as_uint(v);
    return (b & 0x80000000u) ? ~b : (b | 0x80000000u);
}
__device__ __forceinline__ float dec(unsigned k) {
    unsigned b = (k & 0x80000000u) ? (k & 0x7FFFFFFFu) : ~k;
    return __uint_as_float(b);
}

// wave-synchronous select over a 256-bin hist; result broadcast to all 64 lanes.
__device__ __forceinline__ void wsel64(const unsigned* hist, unsigned kr,
                                       unsigned& bin, unsigned& newkr) {
    const int lane = threadIdx.x & 63;
    uint4 h = reinterpret_cast<const uint4*>(hist)[lane];
    unsigned lsum = h.x + h.y + h.z + h.w;
    unsigned suf = lsum;
#pragma unroll
    for (int off = 1; off < 64; off <<= 1) {
        unsigned t = __shfl_down(suf, off);
        if (lane + off < 64) suf += t;
    }
    bool cross = (suf >= kr) && (suf - lsum < kr);
    unsigned long long cm = __ballot(cross);
    int cl = (int)__ffsll(cm) - 1;
    unsigned b = 0, nk = 0;
    if (lane == cl) {
        unsigned hb[4] = {h.x, h.y, h.z, h.w};
        unsigned cum = suf - lsum;
        int q = 3;
        for (; q >= 0; --q) { cum += hb[q]; if (cum >= kr) break; }
        b = (unsigned)((lane << 2) + q);
        nk = kr - (cum - hb[q]);
    }
    bin = (unsigned)__shfl((int)b, cl);
    newkr = (unsigned)__shfl((int)nk, cl);
}

__global__ __launch_bounds__(NT, 4) void lnclamp2(const float* __restrict__ in,
                                                  float* __restrict__ out,
                                                  int nrows) {
    __shared__ __align__(16) unsigned hist[256];
    __shared__ __align__(16) unsigned cand[NWAVE][SEGCAP];
    __shared__ int cnt[NWAVE];
    __shared__ unsigned sh_bin, sh_krem;
    __shared__ double redS[NWAVE], redS2[NWAVE];
    __shared__ float sh_mean, sh_istd;

    const int tid = threadIdx.x, lane = tid & 63, wid = tid >> 6;
    const int row0 = blockIdx.x * 2;
    const int row1 = row0 + 1;
    const bool has1 = row1 < nrows;          // block-uniform

    floatx4 r[NR];
    float hv, tv;

    // ---- select over register-resident row: fills sh_mean / sh_istd ----
    // (block-wide; all threads must enter; fastok path is block-uniform)
    auto SELECT = [&](const float* rp, int first, int nvec, int ti) {
        if (tid < NWAVE) cnt[tid] = 0;
        __syncthreads();
        auto emit = [&](float v) {
            if (v >= TF0) {
                int p = atomicAdd(&cnt[wid], 1);
                if (p < SEGCAP) cand[wid][p] = enc(clipf(v));
            }
        };
        if (tid < first) emit(hv);
#pragma unroll
        for (int q = 0; q < NR - 1; ++q) {
            emit(r[q].x); emit(r[q].y); emit(r[q].z); emit(r[q].w);
        }
        {
            int j = tid + (NR - 1) * NT;
            if (j < nvec) { emit(r[NR-1].x); emit(r[NR-1].y); emit(r[NR-1].z); emit(r[NR-1].w); }
        }
        if (ti < V) emit(tv);
        __syncthreads();

        int ncand = 0;
        bool segok = true;
#pragma unroll
        for (int w = 0; w < NWAVE; ++w) {
            ncand += cnt[w];
            segok = segok && (cnt[w] <= SEGCAP);
        }
        const bool fastok = segok && (ncand >= TOPK);

        unsigned T, krem;
        double s = 0.0, s2 = 0.0;
        if (fastok) {
            unsigned prefix = 0, pmask = 0, kr = TOPK;
            for (int level = 0; level < 4; ++level) {
                const int shift = 24 - 8 * level;
                __syncthreads();
                hist[tid] = 0;
                __syncthreads();
#pragma unroll
                for (int w = 0; w < NWAVE; ++w) {
                    const int c = cnt[w];
                    for (int i = tid; i < c; i += NT) {
                        unsigned k = cand[w][i];
                        if ((k & pmask) == prefix) atomicAdd(&hist[(k >> shift) & 255u], 1u);
                    }
                }
                __syncthreads();
                if (tid < 64) {
                    unsigned bin, nk;
                    wsel64(hist, kr, bin, nk);
                    if (lane == 0) { sh_bin = bin; sh_krem = nk; }
                }
                __syncthreads();
                prefix |= sh_bin << shift;
                pmask |= 255u << shift;
                kr = sh_krem;
            }
            T = prefix; krem = kr;
#pragma unroll
            for (int w = 0; w < NWAVE; ++w) {
                const int c = cnt[w];
                for (int i = tid; i < c; i += NT) {
                    unsigned k = cand[w][i];
                    if (k > T) { double dv = (double)dec(k); s += dv; s2 += dv * dv; }
                }
            }
        } else {
            // exact fallback: block-wide 4-pass MSB radix from global (any data)
            unsigned prefix = 0, pmask = 0, kr = TOPK;
            for (int level = 0; level < 4; ++level) {
                const int shift = 24 - 8 * level;
                __syncthreads();
                hist[tid] = 0;
                __syncthreads();
                for (int i = tid; i < V; i += NT) {
                    unsigned k = enc(clipf(rp[i]));
                    if ((k & pmask) == prefix) atomicAdd(&hist[(k >> shift) & 255u], 1u);
                }
                __syncthreads();
                if (tid < 64) {
                    unsigned bin, nk;
                    wsel64(hist, kr, bin, nk);
                    if (lane == 0) { sh_bin = bin; sh_krem = nk; }
                }
                __syncthreads();
                prefix |= sh_bin << shift;
                pmask |= 255u << shift;
                kr = sh_krem;
            }
            T = prefix; krem = kr;
            for (int i = tid; i < V; i += NT) {
                float v = clipf(rp[i]);
                if (enc(v) > T) { double dv = v; s += dv; s2 += dv * dv; }
            }
        }

        for (int off = 32; off > 0; off >>= 1) {
            s += __shfl_down(s, off); s2 += __shfl_down(s2, off);
        }
        if (lane == 0) { redS[wid] = s; redS2[wid] = s2; }
        __syncthreads();
        if (tid == 0) {
            double S = 0.0, S2 = 0.0;
            for (int w = 0; w < NWAVE; ++w) { S += redS[w]; S2 += redS2[w]; }
            const double vT = (double)dec(T);
            S += (double)krem * vT;
            S2 += (double)krem * vT * vT;
            const double mean = S / (double)TOPK;
            const double var = (S2 - S * S / (double)TOPK) / (double)(TOPK - 1);
            sh_mean = (float)mean;
            sh_istd = (float)(1.0 / sqrt(var + 1e-8));
        }
        __syncthreads();
    };

    // GELU tanh-form via exp: g = n*(1-r2), r2 = 1/(1+exp(1.5957691*(n+0.044715*n^3)))
    auto mkoutf = [&](float istd, float c1) {
        return [=](float v) -> float {
            float n = fmaf(clipf(v), istd, c1);
            float t1 = n * n;
            float t3 = fmaf(t1 * n, 0.044715f, n);
            float e = __expf(1.59576912160573f * t3);
            float r2 = __frcp_rn(1.0f + e);
            float w = fmaf(-0.4f, r2, 0.4f);
            return n * w;
        };
    };

    // ---------------- row 0: load -> select ----------------
    const float* rp0 = in + (size_t)row0 * V;
    float* op0 = out + (size_t)row0 * V;
    const int first0 = (4 - (row0 & 3)) & 3;
    const int nvec0 = (V - first0) >> 2;
    const int ti0 = first0 + (nvec0 << 2) + tid;
    const floatx4* vp0 = reinterpret_cast<const floatx4*>(rp0 + first0);
    floatx4* ovp0 = reinterpret_cast<floatx4*>(op0 + first0);

#pragma unroll
    for (int q = 0; q < NR - 1; ++q)          // q<=20: tid+q*NT <= 5375 < nvec always
        r[q] = __builtin_nontemporal_load(vp0 + tid + q * NT);
    {
        int j = tid + (NR - 1) * NT;
        if (j < nvec0) r[NR - 1] = __builtin_nontemporal_load(vp0 + j);
    }
    hv = (tid < first0) ? rp0[tid] : 0.0f;
    tv = (ti0 < V) ? rp0[ti0] : 0.0f;

    SELECT(rp0, first0, nvec0, ti0);
    const float istd0 = sh_istd;
    const float c10 = -sh_mean * istd0 - 1.0f;
    auto outf0 = mkoutf(istd0, c10);

    // row-1 geometry
    const float* rp1 = in + (size_t)row1 * V;
    float* op1 = out + (size_t)row1 * V;
    const int first1 = (4 - (row1 & 3)) & 3;
    const int nvec1 = (V - first1) >> 2;
    const int ti1 = first1 + (nvec1 << 2) + tid;
    const floatx4* vp1 = reinterpret_cast<const floatx4*>(rp1 + first1);
    floatx4* ovp1 = reinterpret_cast<floatx4*>(op1 + first1);

    if (has1) {
        // ---------- mixed phase: store row0 + load row1 on the same buffer ----------
        if (tid < first0) op0[tid] = outf0(hv);
        if (ti0 < V) op0[ti0] = outf0(tv);
        float nhv = (tid < first1) ? rp1[tid] : 0.0f;
        float ntv = (ti1 < V) ? rp1[ti1] : 0.0f;
#pragma unroll
        for (int q = 0; q < NR - 1; ++q) {
            floatx4 o;
            o.x = outf0(r[q].x); o.y = outf0(r[q].y);
            o.z = outf0(r[q].z); o.w = outf0(r[q].w);
            __builtin_nontemporal_store(o, ovp0 + tid + q * NT);
            r[q] = __builtin_nontemporal_load(vp1 + tid + q * NT);
        }
        {
            int j = tid + (NR - 1) * NT;
            if (j < nvec0) {
                floatx4 o;
                o.x = outf0(r[NR-1].x); o.y = outf0(r[NR-1].y);
                o.z = outf0(r[NR-1].z); o.w = outf0(r[NR-1].w);
                __builtin_nontemporal_store(o, ovp0 + j);
            }
            if (j < nvec1) r[NR - 1] = __builtin_nontemporal_load(vp1 + j);
        }
        hv = nhv; tv = ntv;

        // ---------- row 1: select -> store ----------
        SELECT(rp1, first1, nvec1, ti1);
        const float istd1 = sh_istd;
        const float c11 = -sh_mean * istd1 - 1.0f;
        auto outf1 = mkoutf(istd1, c11);

        if (tid < first1) op1[tid] = outf1(hv);
        if (ti1 < V) op1[ti1] = outf1(tv);
#pragma unroll
        for (int q = 0; q < NR - 1; ++q) {
            floatx4 o;
            o.x = outf1(r[q].x); o.y = outf1(r[q].y);
            o.z = outf1(r[q].z); o.w = outf1(r[q].w);
            __builtin_nontemporal_store(o, ovp1 + tid + q * NT);
        }
        {
            int j = tid + (NR - 1) * NT;
            if (j < nvec1) {
                floatx4 o;
                o.x = outf1(r[NR-1].x); o.y = outf1(r[NR-1].y);
                o.z = outf1(r[NR-1].z); o.w = outf1(r[NR-1].w);
                __builtin_nontemporal_store(o, ovp1 + j);
            }
        }
    } else {
        // last (odd) row alone: plain store
        if (tid < first0) op0[tid] = outf0(hv);
        if (ti0 < V) op0[ti0] = outf0(tv);
#pragma unroll
        for (int q = 0; q < NR - 1; ++q) {
            floatx4 o;
            o.x = outf0(r[q].x); o.y = outf0(r[q].y);
            o.z = outf0(r[q].z); o.w = outf0(r[q].w);
            __builtin_nontemporal_store(o, ovp0 + tid + q * NT);
        }
        {
            int j = tid + (NR - 1) * NT;
            if (j < nvec0) {
                floatx4 o;
                o.x = outf0(r[NR-1].x); o.y = outf0(r[NR-1].y);
                o.z = outf0(r[NR-1].z); o.w = outf0(r[NR-1].w);
                __builtin_nontemporal_store(o, ovp0 + j);
            }
        }
    }
}

extern "C" void kernel_launch(void* const* d_in, const int* in_sizes, int n_in,
                              void* d_out, int out_size, void* d_ws, size_t ws_size,
                              hipStream_t stream) {
    const float* in = (const float*)d_in[0];
    float* out = (float*)d_out;
    const int rows = out_size / V;            // 2048
    const int nb = (rows + 1) / 2;            // 1024 -> 4 blocks/CU, one generation
    hipLaunchKernelGGL(lnclamp2, dim3(nb), dim3(NT), 0, stream, in, out, rows);
}